// Round 13
// baseline (1821.016 us; speedup 1.0000x reference)
//
#include <hip/hip_runtime.h>

typedef _Float16 f16;
typedef _Float16 f16x8 __attribute__((ext_vector_type(8)));
typedef float f32x4 __attribute__((ext_vector_type(4)));

typedef const __attribute__((address_space(1))) void GV;
typedef __attribute__((address_space(3))) void LV;

__device__ __forceinline__ void gload16(const void* g, void* l) {
  __builtin_amdgcn_global_load_lds((GV*)g, (LV*)l, 16, 0, 0);
}

#define WAIT_VM0() asm volatile("s_waitcnt vmcnt(0)" ::: "memory")

// coherent-point access: bypass L1+L2 both sides
__device__ __forceinline__ f16x8 ntload16(const f16* p) {
  f16x8 v;
  asm volatile("global_load_dwordx4 %0, %1, off sc0 sc1" : "=v"(v) : "v"(p) : "memory");
  return v;
}
__device__ __forceinline__ void ntstore16(f16* p, f16x8 v) {
  asm volatile("global_store_dwordx4 %0, %1, off sc0 sc1" :: "v"(p), "v"(v) : "memory");
}

// R4/R11-PROVEN rendezvous: relaxed device-scope atomicAdd + sc0sc1 spin
// (tid 0 only; load+waitcnt fused in ONE asm). No cache maintenance.
__device__ __forceinline__ void group_sync(unsigned* bar, unsigned target) {
  __syncthreads();  // drains vmcnt: all prior sc0sc1 stores are at the IC
  if (threadIdx.x == 0) {
    atomicAdd(bar, 1u);
    int guard = 0;
    while (1) {
      unsigned v;
      asm volatile("global_load_dword %0, %1, off sc0 sc1\n\ts_waitcnt vmcnt(0)"
                   : "=v"(v) : "v"(bar) : "memory");
      if (v >= target || ++guard > (1 << 22)) break;
      __builtin_amdgcn_s_sleep(8);
    }
  }
  __syncthreads();
}

// ---- fragment helpers ----
__device__ __forceinline__ f16x8 frag64(const f16* T, int row, int chunk) {
  int ch = chunk ^ (row & 7);
  return *(const f16x8*)((const char*)T + row * 128 + ch * 16);
}
__device__ __forceinline__ f16x8 frag128(const f16* T, int row, int chunk) {
  int ch = chunk ^ (row & 15);
  return *(const f16x8*)((const char*)T + row * 256 + ch * 16);
}
__device__ __forceinline__ f16* elem128(f16* T, int row, int col) {
  return (f16*)((char*)T + row * 256 + (((col >> 3) ^ (row & 15)) << 4) + (col & 7) * 2);
}

#define MFMA(a, b, c) __builtin_amdgcn_mfma_f32_16x16x32_f16(a, b, c, 0, 0, 0)

__device__ __forceinline__ float sigm(float v) {
  return __builtin_amdgcn_rcpf(1.f + __expf(-v));
}
__device__ __forceinline__ float tanh_(float v) {
  return 1.f - 2.f * __builtin_amdgcn_rcpf(1.f + __expf(2.f * v));
}

// stage one 64-wide K-chunk: A -> LDS (global_load_lds), B -> regs (sc0sc1)
__device__ __forceinline__ void issue64(const f16* Ab, const f16* Bb, int k0,
                                        char* bufA, f16x8 (&c)[4],
                                        const size_t (&offs)[4], int wb) {
#pragma unroll
  for (int q = 0; q < 4; ++q)
    gload16(Ab + k0 + offs[q], bufA + q * 4096 + wb);
#pragma unroll
  for (int q = 0; q < 4; ++q)
    c[q] = ntload16(Bb + k0 + offs[q]);
}
__device__ __forceinline__ void wr64(char* bufB, const f16x8 (&c)[4], int tb) {
#pragma unroll
  for (int q = 0; q < 4; ++q)
    *(f16x8*)(bufB + q * 4096 + tb) = c[q];
}
__device__ __forceinline__ void comp64(const char* buf, int wm, int wn, int g, int r,
                                       f32x4 (&acc)[4][4]) {
  const f16* Ta = (const f16*)buf;
  const f16* Tb = (const f16*)(buf + 16384);
#pragma unroll
  for (int kk = 0; kk < 2; ++kk) {
    f16x8 af[4], bf[4];
#pragma unroll
    for (int i = 0; i < 4; ++i) af[i] = frag64(Ta, wm + i * 16 + r, (kk << 2) | g);
#pragma unroll
    for (int j = 0; j < 4; ++j) bf[j] = frag64(Tb, wn + j * 16 + r, (kk << 2) | g);
#pragma unroll
    for (int i = 0; i < 4; ++i)
#pragma unroll
      for (int j = 0; j < 4; ++j)
        acc[i][j] = MFMA(af[i], bf[j], acc[i][j]);
  }
}

// K=512 GEMM: 8 x 64-wide chunks, 2 ping-pong buffers (engine-local base),
// R4 discipline: issue k+1, compute k, WAIT_VM0 + B-write, __syncthreads.
__device__ __forceinline__ void phase1(const f16* At, const f16* Bb, char* base,
    const size_t (&offs)[4], int ltid, int wm, int wn, int g, int r,
    f32x4 (&acc)[4][4]) {
  const int wb = (ltid >> 6) * 1024;
  const int tb = ltid * 16;
  f16x8 c[4];
  issue64(At, Bb, 0, base, c, offs, wb);
  WAIT_VM0();
  wr64(base + 16384, c, tb);
  __syncthreads();
#pragma unroll 1
  for (int kt = 0; kt < 8; ++kt) {
    char* cur = base + (kt & 1) * 32768;
    char* nxt = base + ((kt & 1) ^ 1) * 32768;
    if (kt < 7) issue64(At, Bb, (kt + 1) * 64, nxt, c, offs, wb);
    comp64(cur, wm, wn, g, r, acc);
    if (kt < 7) { WAIT_VM0(); wr64(nxt + 16384, c, tb); }
    __syncthreads();
  }
}

// acc(node,h-out) = Gs @ WT^T, weights streamed from global (L2-hot)
__device__ __forceinline__ void gate_gemm(const f16* Gs, const f16* WT,
                                          int wm, int wn, int g, int r,
                                          f32x4 (&acc)[4][4]) {
#pragma unroll
  for (int kk = 0; kk < 4; ++kk) {
    f16x8 wf[4], af[4];
#pragma unroll
    for (int j = 0; j < 4; ++j)
      wf[j] = *(const f16x8*)&WT[(size_t)(wn + j * 16 + r) * 128 + kk * 32 + g * 8];
#pragma unroll
    for (int i = 0; i < 4; ++i) af[i] = frag128(Gs, wm + i * 16 + r, (kk << 2) | g);
#pragma unroll
    for (int i = 0; i < 4; ++i)
#pragma unroll
      for (int j = 0; j < 4; ++j)
        acc[i][j] = MFMA(af[i], wf[j], acc[i][j]);
  }
}

// 512 threads = 2 engines x 4 waves. Engine e owns node-tile
// nc = (blockIdx&1)*2 + e. 1 block/CU x 8 waves = 2 waves/SIMD (248 VGPR x 2
// = 496 <= 512/SIMD). R12 ERRATum: launch_bounds 2nd arg 2 acted as CUDA-style
// min-BLOCKS/CU -> 128-VGPR cap -> spills (+0.58GB traffic). Use 1.
__global__ __launch_bounds__(512, 1)
void persist(const f16* __restrict__ A16, const f16* __restrict__ AX,
             const f16* __restrict__ WzT, const f16* __restrict__ WrT,
             const f16* __restrict__ WhT,
             const float* __restrict__ Wzf, const float* __restrict__ bz,
             const float* __restrict__ Wrf, const float* __restrict__ br,
             const float* __restrict__ Whf, const float* __restrict__ bh,
             const float* __restrict__ Whead, const float* __restrict__ bhead,
             f16* __restrict__ Ha, f16* __restrict__ Hb,
             f16* __restrict__ RH, unsigned* __restrict__ bar,
             float* __restrict__ out) {
  __shared__ __align__(16) char sm[136704];
  // engine e at sm+e*65536: staging ping-pong 2x(A16K|B16K).
  // Gs aliases buf1 (32768..65536), Ct aliases buf0 (0..32768) - both dead
  // during phase1 (audited). Tails: AXs 2x512B @131072, wp 1152 f32 @132096.

  const int tid = threadIdx.x;
  const int e = tid >> 8;
  const int ltid = tid & 255;
  const int lane = ltid & 63;
  const int g = lane >> 4, r = lane & 15;
  const int wid4 = (ltid >> 6) & 3;
  const int wm = (wid4 >> 1) * 64, wn = (wid4 & 1) * 64;
  const int b = blockIdx.x >> 1, half = blockIdx.x & 1;
  const int nc = half * 2 + e;
  const int m0 = nc * 128;

  char* eng = sm + e * 65536;
  f16* Gs = (f16*)(eng + 32768);
  f16* Ct = (f16*)(eng + 0);
  f16* AXs = (f16*)(sm + 131072) + e * 256;
  float* wp = (float*)(sm + 132096);

  for (int idx = tid; idx < 1152; idx += 512) {
    int row = idx >> 7, j = idx & 127;
    float v;
    if (row == 0) v = Wzf[j];
    else if (row == 1) v = Wzf[128 + j];
    else if (row == 2) v = bz[j];
    else if (row == 3) v = Wrf[j];
    else if (row == 4) v = Wrf[128 + j];
    else if (row == 5) v = br[j];
    else if (row == 6) v = Whf[j];
    else if (row == 7) v = Whf[128 + j];
    else v = bh[j];
    wp[idx] = v;
  }

  // swizzled per-thread offsets into a [128][64] chunk of an ld=512 source
  size_t offs[4];
#pragma unroll
  for (int q = 0; q < 4; ++q) {
    int lin = q * 4096 + ltid * 16;
    int row = lin >> 7;
    int ch = ((lin >> 4) & 7) ^ (row & 7);
    offs[q] = (size_t)row * 512 + ch * 8;
  }

  const f16* Atile = A16 + (size_t)m0 * 512;
  const size_t boff = (size_t)b * 65536;
  f16* rh = RH + boff;
  unsigned* mybar = bar + b * 16;
  unsigned nbar = 0;
  f16x8 zreg[8];
  f16x8 hvreg[8] = {};  // own h tile [hh][node], carried across steps (h0=0)
  __syncthreads();

#pragma unroll 1
  for (int t = 0; t < 24; ++t) {
    const f16* hc = ((t & 1) ? Hb : Ha) + boff;
    f16* hn = ((t & 1) ? Ha : Hb) + boff;
    if (ltid < 128) {
      int cf = b * 48 + t * 2;
      const f16* p = AX + (size_t)(cf >> 7) * 65536 + (size_t)(m0 + ltid) * 128 + (cf & 127);
      AXs[2 * ltid] = p[0];
      AXs[2 * ltid + 1] = p[1];
    }
    // ---- phase 1A: G = A @ h ----
    f32x4 acc[4][4] = {};
    phase1(Atile, hc, eng, offs, ltid, wm, wn, g, r, acc);
#pragma unroll
    for (int i = 0; i < 4; ++i)
#pragma unroll
      for (int j = 0; j < 4; ++j)
#pragma unroll
        for (int q = 0; q < 4; ++q)
          *elem128(Gs, wm + i * 16 + g * 4 + q, wn + j * 16 + r) = (f16)acc[i][j][q];
    __syncthreads();
    // ---- z gate (stays in registers) ----
    {
      f32x4 az[4][4] = {};
      gate_gemm(Gs, WzT, wm, wn, g, r, az);
#pragma unroll
      for (int i = 0; i < 4; ++i)
#pragma unroll
        for (int j = 0; j < 4; ++j)
#pragma unroll
          for (int q = 0; q < 4; ++q)
            *elem128(Ct, wn + j * 16 + r, wm + i * 16 + g * 4 + q) = (f16)az[i][j][q];
      __syncthreads();
#pragma unroll
      for (int p = 0; p < 8; ++p) {
        int hh = p * 16 + (ltid >> 4), c = ltid & 15, nl0 = c * 8;
        f16x8 cv = frag128(Ct, hh, c);
        float w0 = wp[hh], w1 = wp[128 + hh], bb = wp[256 + hh];
        f16x8 o;
#pragma unroll
        for (int u = 0; u < 8; ++u) {
          int nl = nl0 + u;
          float gx = (float)AXs[2 * nl] * w0 + (float)AXs[2 * nl + 1] * w1 + bb;
          o[u] = (f16)sigm((float)cv[u] + gx);
        }
        zreg[p] = o;
      }
      __syncthreads();
    }
    // ---- r gate -> rh = r*h (coherent store, group-shared) ----
    {
      f32x4 ar[4][4] = {};
      gate_gemm(Gs, WrT, wm, wn, g, r, ar);
#pragma unroll
      for (int i = 0; i < 4; ++i)
#pragma unroll
        for (int j = 0; j < 4; ++j)
#pragma unroll
          for (int q = 0; q < 4; ++q)
            *elem128(Ct, wn + j * 16 + r, wm + i * 16 + g * 4 + q) = (f16)ar[i][j][q];
      __syncthreads();
#pragma unroll
      for (int p = 0; p < 8; ++p) {
        int hh = p * 16 + (ltid >> 4), c = ltid & 15, nl0 = c * 8;
        f16x8 cv = frag128(Ct, hh, c);
        f16x8 hv = hvreg[p];
        float w0 = wp[384 + hh], w1 = wp[512 + hh], bb = wp[640 + hh];
        f16x8 o;
#pragma unroll
        for (int u = 0; u < 8; ++u) {
          int nl = nl0 + u;
          float gx = (float)AXs[2 * nl] * w0 + (float)AXs[2 * nl + 1] * w1 + bb;
          float rv = sigm((float)cv[u] + gx);
          o[u] = (f16)(rv * (float)hv[u]);
        }
        ntstore16(&rh[(size_t)hh * 512 + m0 + nl0], o);
      }
      WAIT_VM0();
    }
    group_sync(mybar, 2u * (++nbar));
    // ---- phase 1B: Gh = A @ (r*h) ----
    f32x4 acc2[4][4] = {};
    phase1(Atile, rh, eng, offs, ltid, wm, wn, g, r, acc2);
#pragma unroll
    for (int i = 0; i < 4; ++i)
#pragma unroll
      for (int j = 0; j < 4; ++j)
#pragma unroll
        for (int q = 0; q < 4; ++q)
          *elem128(Gs, wm + i * 16 + g * 4 + q, wn + j * 16 + r) = (f16)acc2[i][j][q];
    __syncthreads();
    // ---- h_tilde + update ----
    {
      f32x4 ah[4][4] = {};
      gate_gemm(Gs, WhT, wm, wn, g, r, ah);
#pragma unroll
      for (int i = 0; i < 4; ++i)
#pragma unroll
        for (int j = 0; j < 4; ++j)
#pragma unroll
          for (int q = 0; q < 4; ++q)
            *elem128(Ct, wn + j * 16 + r, wm + i * 16 + g * 4 + q) = (f16)ah[i][j][q];
      __syncthreads();
#pragma unroll
      for (int p = 0; p < 8; ++p) {
        int hh = p * 16 + (ltid >> 4), c = ltid & 15, nl0 = c * 8;
        f16x8 cv = frag128(Ct, hh, c);
        float w0 = wp[768 + hh], w1 = wp[896 + hh], bb = wp[1024 + hh];
        f16x8 hv = hvreg[p], zv = zreg[p];
        f16x8 o;
#pragma unroll
        for (int u = 0; u < 8; ++u) {
          int nl = nl0 + u;
          float gx = (float)AXs[2 * nl] * w0 + (float)AXs[2 * nl + 1] * w1 + bb;
          float ht = tanh_((float)cv[u] + gx);
          float z = (float)zv[u];
          o[u] = (f16)((1.f - z) * (float)hv[u] + z * ht);
        }
        hvreg[p] = o;
        if (t < 23) {
          ntstore16(&hn[(size_t)hh * 512 + m0 + nl0], o);
        } else {
          *(f16x8*)((char*)Gs + hh * 256 + nl0 * 2) = o;  // final h, linear [h][node]
        }
      }
      if (t < 23) WAIT_VM0();
    }
    if (t < 23) {
      group_sync(mybar, 2u * (++nbar));
    }
  }

  // ---- head: out[b, :, m0..m0+127] from final h in engine LDS ----
  __syncthreads();
  float* Ws = (float*)Ct;                       // 6192B in buf0
  for (int idx = ltid; idx < 1548; idx += 256)
    Ws[idx] = (idx < 1536) ? Whead[idx] : bhead[idx - 1536];
  __syncthreads();
  {
    int n = ltid & 127, hf = ltid >> 7;
    float pa[12];
#pragma unroll
    for (int o = 0; o < 12; ++o) pa[o] = 0.f;
    const f16* Hfin = (const f16*)Gs;
    for (int h = hf * 64; h < hf * 64 + 64; ++h) {
      float v = (float)Hfin[h * 128 + n];
#pragma unroll
      for (int o = 0; o < 12; ++o) pa[o] = fmaf(v, Ws[h * 12 + o], pa[o]);
    }
    float* P = (float*)(eng + 16384);           // 12KB in buf0 tail
#pragma unroll
    for (int o = 0; o < 12; ++o) P[(n * 2 + hf) * 12 + o] = pa[o];
    __syncthreads();
    if (hf == 0) {
#pragma unroll
      for (int o = 0; o < 12; ++o)
        out[(size_t)b * 6144 + o * 512 + m0 + n] =
            P[n * 24 + o] + P[n * 24 + 12 + o] + Ws[1536 + o];
    }
  }
}

// ---------- setup kernels (one-time) ----------
__device__ __forceinline__ void stage128x64(const f16* src, int row0, int ld, int k0,
                                            f16* lds, int tid) {
  int wid = tid >> 6;
#pragma unroll
  for (int q = 0; q < 4; ++q) {
    int lin = q * 4096 + tid * 16;
    int row = lin >> 7;
    int ch = (lin >> 4) & 7;
    int sch = ch ^ (row & 7);
    gload16(src + (size_t)(row0 + row) * ld + k0 + sch * 8,
            (char*)lds + q * 4096 + wid * 1024);
  }
}

__global__ __launch_bounds__(256, 2)
void gemm512(const f16* __restrict__ A, const f16* __restrict__ B,
             f16* __restrict__ C) {
  __shared__ __align__(16) char sm[34816];
  f16* As = (f16*)sm;
  f16* Bs = (f16*)(sm + 16384);
  const int tid = threadIdx.x;
  const int lane = tid & 63;
  const int g = lane >> 4, r = lane & 15;
  const int wid = tid >> 6;
  const int wm = (wid >> 1) * 64, wn = (wid & 1) * 64;
  const int m0 = blockIdx.y * 128;
  const int n0 = blockIdx.x * 128;
  f32x4 acc[4][4] = {};
  for (int kt = 0; kt < 8; ++kt) {
    stage128x64(A, m0, 512, kt * 64, As, tid);
    stage128x64(B, n0, 512, kt * 64, Bs, tid);
    __syncthreads();
#pragma unroll
    for (int kk = 0; kk < 2; ++kk) {
      f16x8 af[4], bf[4];
#pragma unroll
      for (int i = 0; i < 4; ++i) af[i] = frag64(As, wm + i * 16 + r, (kk << 2) | g);
#pragma unroll
      for (int j = 0; j < 4; ++j) bf[j] = frag64(Bs, wn + j * 16 + r, (kk << 2) | g);
#pragma unroll
      for (int i = 0; i < 4; ++i)
#pragma unroll
        for (int j = 0; j < 4; ++j)
          acc[i][j] = MFMA(af[i], bf[j], acc[i][j]);
    }
    __syncthreads();
  }
  f16* Ctl = (f16*)sm;
#pragma unroll
  for (int i = 0; i < 4; ++i)
#pragma unroll
    for (int j = 0; j < 4; ++j) {
      int col = wn + j * 16 + r;
#pragma unroll
      for (int q = 0; q < 4; ++q) {
        int row = wm + i * 16 + g * 4 + q;
        Ctl[row * 136 + col] = (f16)acc[i][j][q];
      }
    }
  __syncthreads();
  f16* Cb = C + (size_t)blockIdx.x * 65536;
#pragma unroll
  for (int p = 0; p < 8; ++p) {
    int row = p * 16 + (tid >> 4);
    int c0 = (tid & 15) * 8;
    f16x8 v = *(const f16x8*)&Ctl[row * 136 + c0];
    *(f16x8*)&Cb[(size_t)(m0 + row) * 128 + c0] = v;
  }
}

__global__ void m12k(const float* __restrict__ E, const float* __restrict__ W1,
                     const float* __restrict__ W2, float* __restrict__ M1,
                     float* __restrict__ M2) {
  int idx = blockIdx.x * 256 + threadIdx.x;
  if (idx >= 16384) return;
  int which = idx >> 13;
  int rem = idx & 8191;
  int n = rem >> 4, j = rem & 15;
  const float* W = which ? W2 : W1;
  float s = 0.f;
#pragma unroll
  for (int k = 0; k < 16; ++k) s += E[n * 16 + k] * W[k * 16 + j];
  (which ? M2 : M1)[n * 16 + j] = s;
}

__global__ __launch_bounds__(256)
void softA(const float* __restrict__ M1, const float* __restrict__ M2,
           f16* __restrict__ A16) {
  __shared__ float M2s[8192];
  __shared__ float m1s[16];
  __shared__ float red[8];
  int i = blockIdx.x, tid = threadIdx.x;
  for (int q = tid; q < 8192; q += 256) M2s[q] = M2[q];
  if (tid < 16) m1s[tid] = M1[i * 16 + tid];
  __syncthreads();
  float s0 = 0.f, s1 = 0.f;
#pragma unroll
  for (int k = 0; k < 16; ++k) {
    float a = m1s[k];
    s0 += a * M2s[tid * 16 + k];
    s1 += a * M2s[(tid + 256) * 16 + k];
  }
  s0 = fmaxf(s0, 0.f);
  s1 = fmaxf(s1, 0.f);
  float m = fmaxf(s0, s1);
  for (int o = 32; o > 0; o >>= 1) m = fmaxf(m, __shfl_xor(m, o));
  if ((tid & 63) == 0) red[tid >> 6] = m;
  __syncthreads();
  m = fmaxf(fmaxf(red[0], red[1]), fmaxf(red[2], red[3]));
  float e0 = expf(s0 - m), e1 = expf(s1 - m);
  float ss = e0 + e1;
  for (int o = 32; o > 0; o >>= 1) ss += __shfl_xor(ss, o);
  __syncthreads();
  if ((tid & 63) == 0) red[4 + (tid >> 6)] = ss;
  __syncthreads();
  ss = (red[4] + red[5]) + (red[6] + red[7]);
  float inv = 1.f / ss;
  A16[(size_t)i * 512 + tid] = (f16)(e0 * inv);
  A16[(size_t)i * 512 + tid + 256] = (f16)(e1 * inv);
}

__global__ void wTk(const float* __restrict__ Wz, const float* __restrict__ Wr,
                    const float* __restrict__ Wh, f16* __restrict__ WzT,
                    f16* __restrict__ WrT, f16* __restrict__ WhT) {
  int idx = blockIdx.x * 256 + threadIdx.x;
  if (idx >= 49152) return;
  int w = idx / 16384;
  int rem = idx & 16383;
  int hp = rem >> 7, k = rem & 127;
  const float* S = (w == 0) ? Wz : ((w == 1) ? Wr : Wh);
  f16* D = (w == 0) ? WzT : ((w == 1) ? WrT : WhT);
  D[hp * 128 + k] = (f16)S[(2 + k) * 128 + hp];
}

__global__ void xTk(const float* __restrict__ X, f16* __restrict__ XTT) {
  int idx = blockIdx.x * 256 + threadIdx.x;
  if (idx >= 786432) return;
  int m = idx & 511;
  int bt = idx >> 9;
  float x0 = X[(size_t)idx * 2];
  float x1 = X[(size_t)idx * 2 + 1];
  XTT[(size_t)(bt * 2 + 0) * 512 + m] = (f16)x0;
  XTT[(size_t)(bt * 2 + 1) * 512 + m] = (f16)x1;
}

extern "C" void kernel_launch(void* const* d_in, const int* in_sizes, int n_in,
                              void* d_out, int out_size, void* d_ws, size_t ws_size,
                              hipStream_t stream) {
  (void)in_sizes; (void)n_in; (void)out_size; (void)ws_size;
  const float* X = (const float*)d_in[0];
  const float* E = (const float*)d_in[1];
  const float* W1 = (const float*)d_in[2];
  const float* W2 = (const float*)d_in[3];
  const float* Wz = (const float*)d_in[4];
  const float* bz = (const float*)d_in[5];
  const float* Wr = (const float*)d_in[6];
  const float* br = (const float*)d_in[7];
  const float* Wh = (const float*)d_in[8];
  const float* bh = (const float*)d_in[9];
  const float* Whead = (const float*)d_in[10];
  const float* bhead = (const float*)d_in[11];
  float* out = (float*)d_out;
  char* ws = (char*)d_ws;

  f16* A16 = (f16*)(ws + 0);           // 512x512
  f16* XTT = (f16*)(ws + 524288);      // 3072x512
  f16* AX  = (f16*)(ws + 3670016);     // [24 tiles][512][128]
  f16* Ha  = (f16*)(ws + 6815744);     // [64][128][512]
  f16* Hb  = (f16*)(ws + 15204352);
  f16* RH  = (f16*)(ws + 23592960);    // [64][128][512]
  f16* WzT = (f16*)(ws + 31981568);    // 128x128 f16
  f16* WrT = (f16*)(ws + 32014336);
  f16* WhT = (f16*)(ws + 32047104);
  float* M1 = (float*)(ws + 32079872);
  float* M2 = (float*)(ws + 32112640);
  unsigned* bar = (unsigned*)(ws + 32145408);  // 64 groups x 64B

  hipMemsetAsync(Ha, 0, 8388608, stream);
  hipMemsetAsync(bar, 0, 16384, stream);
  m12k<<<64, 256, 0, stream>>>(E, W1, W2, M1, M2);
  softA<<<512, 256, 0, stream>>>(M1, M2, A16);
  wTk<<<192, 256, 0, stream>>>(Wz, Wr, Wh, WzT, WrT, WhT);
  xTk<<<3072, 256, 0, stream>>>(X, XTT);
  gemm512<<<dim3(24, 4), 256, 0, stream>>>(A16, XTT, AX);
  persist<<<128, 512, 0, stream>>>(A16, AX, WzT, WrT, WhT, Wz, bz, Wr, br, Wh, bh,
                                   Whead, bhead, Ha, Hb, RH, bar, out);
}

// Round 14
// 813.333 us; speedup vs baseline: 2.2390x; 2.2390x over previous
//
#include <hip/hip_runtime.h>

typedef _Float16 f16;
typedef _Float16 f16x8 __attribute__((ext_vector_type(8)));
typedef float f32x4 __attribute__((ext_vector_type(4)));

typedef const __attribute__((address_space(1))) void GV;
typedef __attribute__((address_space(3))) void LV;

__device__ __forceinline__ void gload16(const void* g, void* l) {
  __builtin_amdgcn_global_load_lds((GV*)g, (LV*)l, 16, 0, 0);
}

#define WAIT_VM0() asm volatile("s_waitcnt vmcnt(0)" ::: "memory")

// coherent-point access: bypass L1+L2 both sides
__device__ __forceinline__ f16x8 ntload16(const f16* p) {
  f16x8 v;
  asm volatile("global_load_dwordx4 %0, %1, off sc0 sc1" : "=v"(v) : "v"(p) : "memory");
  return v;
}
__device__ __forceinline__ void ntstore16(f16* p, f16x8 v) {
  asm volatile("global_store_dwordx4 %0, %1, off sc0 sc1" :: "v"(p), "v"(v) : "memory");
}

// R4/R11-PROVEN rendezvous: relaxed device-scope atomicAdd + sc0sc1 spin
// (tid 0 only; load+waitcnt fused in ONE asm). No cache maintenance.
__device__ __forceinline__ void group_sync(unsigned* bar, unsigned target) {
  __syncthreads();  // drains vmcnt: all prior sc0sc1 stores are at the IC
  if (threadIdx.x == 0) {
    atomicAdd(bar, 1u);
    int guard = 0;
    while (1) {
      unsigned v;
      asm volatile("global_load_dword %0, %1, off sc0 sc1\n\ts_waitcnt vmcnt(0)"
                   : "=v"(v) : "v"(bar) : "memory");
      if (v >= target || ++guard > (1 << 22)) break;
      __builtin_amdgcn_s_sleep(8);
    }
  }
  __syncthreads();
}

// ---- fragment helpers ----
__device__ __forceinline__ f16x8 frag64(const f16* T, int row, int chunk) {
  int ch = chunk ^ (row & 7);
  return *(const f16x8*)((const char*)T + row * 128 + ch * 16);
}
__device__ __forceinline__ f16x8 frag128(const f16* T, int row, int chunk) {
  int ch = chunk ^ (row & 15);
  return *(const f16x8*)((const char*)T + row * 256 + ch * 16);
}
__device__ __forceinline__ f16* elem128(f16* T, int row, int col) {
  return (f16*)((char*)T + row * 256 + (((col >> 3) ^ (row & 15)) << 4) + (col & 7) * 2);
}

#define MFMA(a, b, c) __builtin_amdgcn_mfma_f32_16x16x32_f16(a, b, c, 0, 0, 0)

__device__ __forceinline__ float sigm(float v) {
  return __builtin_amdgcn_rcpf(1.f + __expf(-v));
}
__device__ __forceinline__ float tanh_(float v) {
  return 1.f - 2.f * __builtin_amdgcn_rcpf(1.f + __expf(2.f * v));
}

// stage one 64-wide K-chunk: A -> LDS (global_load_lds), B -> regs (sc0sc1)
__device__ __forceinline__ void issue64(const f16* Ab, const f16* Bb, int k0,
                                        char* bufA, f16x8 (&c)[4],
                                        const size_t (&offs)[4], int wb) {
#pragma unroll
  for (int q = 0; q < 4; ++q)
    gload16(Ab + k0 + offs[q], bufA + q * 4096 + wb);
#pragma unroll
  for (int q = 0; q < 4; ++q)
    c[q] = ntload16(Bb + k0 + offs[q]);
}
__device__ __forceinline__ void wr64(char* bufB, const f16x8 (&c)[4], int tb) {
#pragma unroll
  for (int q = 0; q < 4; ++q)
    *(f16x8*)(bufB + q * 4096 + tb) = c[q];
}
__device__ __forceinline__ void comp64(const char* buf, int wm, int wn, int g, int r,
                                       f32x4 (&acc)[4][4]) {
  const f16* Ta = (const f16*)buf;
  const f16* Tb = (const f16*)(buf + 16384);
#pragma unroll
  for (int kk = 0; kk < 2; ++kk) {
    f16x8 af[4], bf[4];
#pragma unroll
    for (int i = 0; i < 4; ++i) af[i] = frag64(Ta, wm + i * 16 + r, (kk << 2) | g);
#pragma unroll
    for (int j = 0; j < 4; ++j) bf[j] = frag64(Tb, wn + j * 16 + r, (kk << 2) | g);
#pragma unroll
    for (int i = 0; i < 4; ++i)
#pragma unroll
      for (int j = 0; j < 4; ++j)
        acc[i][j] = MFMA(af[i], bf[j], acc[i][j]);
  }
}

// K=512 GEMM: 8 x 64-wide chunks, 2 ping-pong buffers, R4 discipline:
// issue k+1, compute k, WAIT_VM0 + B-write, __syncthreads per stage.
__device__ __forceinline__ void phase1(const f16* At, const f16* Bb, char* sm,
    const size_t (&offs)[4], int wm, int wn, int g, int r, f32x4 (&acc)[4][4]) {
  const int tid = threadIdx.x;
  const int wb = (tid >> 6) * 1024;
  const int tb = tid * 16;
  f16x8 c[4];
  issue64(At, Bb, 0, sm, c, offs, wb);
  WAIT_VM0();
  wr64(sm + 16384, c, tb);
  __syncthreads();
#pragma unroll 1
  for (int kt = 0; kt < 8; ++kt) {
    char* cur = sm + (kt & 1) * 32768;
    char* nxt = sm + ((kt & 1) ^ 1) * 32768;
    if (kt < 7) issue64(At, Bb, (kt + 1) * 64, nxt, c, offs, wb);
    comp64(cur, wm, wn, g, r, acc);
    if (kt < 7) { WAIT_VM0(); wr64(nxt + 16384, c, tb); }
    __syncthreads();
  }
}

// acc(node,h-out) = Gs @ WT^T, weights streamed from global (L2-hot)
__device__ __forceinline__ void gate_gemm(const f16* Gs, const f16* WT,
                                          int wm, int wn, int g, int r,
                                          f32x4 (&acc)[4][4]) {
#pragma unroll
  for (int kk = 0; kk < 4; ++kk) {
    f16x8 wf[4], af[4];
#pragma unroll
    for (int j = 0; j < 4; ++j)
      wf[j] = *(const f16x8*)&WT[(size_t)(wn + j * 16 + r) * 128 + kk * 32 + g * 8];
#pragma unroll
    for (int i = 0; i < 4; ++i) af[i] = frag128(Gs, wm + i * 16 + r, (kk << 2) | g);
#pragma unroll
    for (int i = 0; i < 4; ++i)
#pragma unroll
      for (int j = 0; j < 4; ++j)
        acc[i][j] = MFMA(af[i], wf[j], acc[i][j]);
  }
}

// 256 threads (4 waves, ~248 VGPR proven in R11). LDS shrunk to 70656B by
// aliasing Gs=staging-buf1, Ct=staging-buf0 (both dead during phase1;
// barrier-separated — audited) -> 2 blocks/CU = 2 waves/SIMD. R12/R13
// ERRATUM: 512-thread blocks get a hard ~128-VGPR allocation -> spills.
__global__ __launch_bounds__(256, 1)
void persist(const f16* __restrict__ A16, const f16* __restrict__ AX,
             const f16* __restrict__ WzT, const f16* __restrict__ WrT,
             const f16* __restrict__ WhT,
             const float* __restrict__ Wzf, const float* __restrict__ bz,
             const float* __restrict__ Wrf, const float* __restrict__ br,
             const float* __restrict__ Whf, const float* __restrict__ bh,
             const float* __restrict__ Whead, const float* __restrict__ bhead,
             f16* __restrict__ Ha, f16* __restrict__ Hb,
             f16* __restrict__ RH, unsigned* __restrict__ bar,
             float* __restrict__ out) {
  __shared__ __align__(16) char sm[70656];
  // 0..65536: staging ping-pong (2 x [A 16K | B 16K]).
  // Gs aliases buf1 (32768..65536); Ct aliases buf0 (0..32768).
  f16* Gs = (f16*)(sm + 32768);
  f16* Ct = (f16*)(sm + 0);
  f16* AXs = (f16*)(sm + 65536);     // 512B
  float* wp = (float*)(sm + 66048);  // 9*128 f32 = 4608B

  const int tid = threadIdx.x;
  const int lane = tid & 63;
  const int g = lane >> 4, r = lane & 15;
  const int wid = tid >> 6;
  const int wm = (wid >> 1) * 64, wn = (wid & 1) * 64;
  const int b = blockIdx.x >> 2, nc = blockIdx.x & 3;
  const int m0 = nc * 128;

  for (int idx = tid; idx < 1152; idx += 256) {
    int row = idx >> 7, j = idx & 127;
    float v;
    if (row == 0) v = Wzf[j];
    else if (row == 1) v = Wzf[128 + j];
    else if (row == 2) v = bz[j];
    else if (row == 3) v = Wrf[j];
    else if (row == 4) v = Wrf[128 + j];
    else if (row == 5) v = br[j];
    else if (row == 6) v = Whf[j];
    else if (row == 7) v = Whf[128 + j];
    else v = bh[j];
    wp[idx] = v;
  }

  // swizzled per-thread offsets into a [128][64] chunk of an ld=512 source
  size_t offs[4];
#pragma unroll
  for (int q = 0; q < 4; ++q) {
    int lin = q * 4096 + tid * 16;
    int row = lin >> 7;
    int ch = ((lin >> 4) & 7) ^ (row & 7);
    offs[q] = (size_t)row * 512 + ch * 8;
  }

  const f16* Atile = A16 + (size_t)m0 * 512;
  const size_t boff = (size_t)b * 65536;
  f16* rh = RH + boff;
  unsigned* mybar = bar + b * 16;
  unsigned nbar = 0;
  f16x8 zreg[8];
  f16x8 hvreg[8] = {};  // own h tile [hh][node], carried across steps (h0=0)
  __syncthreads();

#pragma unroll 1
  for (int t = 0; t < 24; ++t) {
    const f16* hc = ((t & 1) ? Hb : Ha) + boff;
    f16* hn = ((t & 1) ? Ha : Hb) + boff;
    if (tid < 128) {
      int cf = b * 48 + t * 2;
      const f16* p = AX + (size_t)(cf >> 7) * 65536 + (size_t)(m0 + tid) * 128 + (cf & 127);
      AXs[2 * tid] = p[0];
      AXs[2 * tid + 1] = p[1];
    }
    // ---- phase 1A: G = A @ h ----
    f32x4 acc[4][4] = {};
    phase1(Atile, hc, sm, offs, wm, wn, g, r, acc);
#pragma unroll
    for (int i = 0; i < 4; ++i)
#pragma unroll
      for (int j = 0; j < 4; ++j)
#pragma unroll
        for (int q = 0; q < 4; ++q)
          *elem128(Gs, wm + i * 16 + g * 4 + q, wn + j * 16 + r) = (f16)acc[i][j][q];
    __syncthreads();
    // ---- z gate (stays in registers) ----
    {
      f32x4 az[4][4] = {};
      gate_gemm(Gs, WzT, wm, wn, g, r, az);
#pragma unroll
      for (int i = 0; i < 4; ++i)
#pragma unroll
        for (int j = 0; j < 4; ++j)
#pragma unroll
          for (int q = 0; q < 4; ++q)
            *elem128(Ct, wn + j * 16 + r, wm + i * 16 + g * 4 + q) = (f16)az[i][j][q];
      __syncthreads();
#pragma unroll
      for (int p = 0; p < 8; ++p) {
        int hh = p * 16 + (tid >> 4), c = tid & 15, nl0 = c * 8;
        f16x8 cv = frag128(Ct, hh, c);
        float w0 = wp[hh], w1 = wp[128 + hh], bb = wp[256 + hh];
        f16x8 o;
#pragma unroll
        for (int u = 0; u < 8; ++u) {
          int nl = nl0 + u;
          float gx = (float)AXs[2 * nl] * w0 + (float)AXs[2 * nl + 1] * w1 + bb;
          o[u] = (f16)sigm((float)cv[u] + gx);
        }
        zreg[p] = o;
      }
      __syncthreads();
    }
    // ---- r gate -> rh = r*h (coherent store, group-shared) ----
    {
      f32x4 ar[4][4] = {};
      gate_gemm(Gs, WrT, wm, wn, g, r, ar);
#pragma unroll
      for (int i = 0; i < 4; ++i)
#pragma unroll
        for (int j = 0; j < 4; ++j)
#pragma unroll
          for (int q = 0; q < 4; ++q)
            *elem128(Ct, wn + j * 16 + r, wm + i * 16 + g * 4 + q) = (f16)ar[i][j][q];
      __syncthreads();
#pragma unroll
      for (int p = 0; p < 8; ++p) {
        int hh = p * 16 + (tid >> 4), c = tid & 15, nl0 = c * 8;
        f16x8 cv = frag128(Ct, hh, c);
        f16x8 hv = hvreg[p];
        float w0 = wp[384 + hh], w1 = wp[512 + hh], bb = wp[640 + hh];
        f16x8 o;
#pragma unroll
        for (int u = 0; u < 8; ++u) {
          int nl = nl0 + u;
          float gx = (float)AXs[2 * nl] * w0 + (float)AXs[2 * nl + 1] * w1 + bb;
          float rv = sigm((float)cv[u] + gx);
          o[u] = (f16)(rv * (float)hv[u]);
        }
        ntstore16(&rh[(size_t)hh * 512 + m0 + nl0], o);
      }
      WAIT_VM0();
    }
    group_sync(mybar, 4u * (++nbar));
    // ---- phase 1B: Gh = A @ (r*h) ----
    f32x4 acc2[4][4] = {};
    phase1(Atile, rh, sm, offs, wm, wn, g, r, acc2);
#pragma unroll
    for (int i = 0; i < 4; ++i)
#pragma unroll
      for (int j = 0; j < 4; ++j)
#pragma unroll
        for (int q = 0; q < 4; ++q)
          *elem128(Gs, wm + i * 16 + g * 4 + q, wn + j * 16 + r) = (f16)acc2[i][j][q];
    __syncthreads();
    // ---- h_tilde + update ----
    {
      f32x4 ah[4][4] = {};
      gate_gemm(Gs, WhT, wm, wn, g, r, ah);
#pragma unroll
      for (int i = 0; i < 4; ++i)
#pragma unroll
        for (int j = 0; j < 4; ++j)
#pragma unroll
          for (int q = 0; q < 4; ++q)
            *elem128(Ct, wn + j * 16 + r, wm + i * 16 + g * 4 + q) = (f16)ah[i][j][q];
      __syncthreads();
#pragma unroll
      for (int p = 0; p < 8; ++p) {
        int hh = p * 16 + (tid >> 4), c = tid & 15, nl0 = c * 8;
        f16x8 cv = frag128(Ct, hh, c);
        float w0 = wp[768 + hh], w1 = wp[896 + hh], bb = wp[1024 + hh];
        f16x8 hv = hvreg[p], zv = zreg[p];
        f16x8 o;
#pragma unroll
        for (int u = 0; u < 8; ++u) {
          int nl = nl0 + u;
          float gx = (float)AXs[2 * nl] * w0 + (float)AXs[2 * nl + 1] * w1 + bb;
          float ht = tanh_((float)cv[u] + gx);
          float z = (float)zv[u];
          o[u] = (f16)((1.f - z) * (float)hv[u] + z * ht);
        }
        hvreg[p] = o;
        if (t < 23) {
          ntstore16(&hn[(size_t)hh * 512 + m0 + nl0], o);
        } else {
          *(f16x8*)((char*)Gs + hh * 256 + nl0 * 2) = o;  // final h, linear [h][node]
        }
      }
      if (t < 23) WAIT_VM0();
    }
    if (t < 23) {
      group_sync(mybar, 4u * (++nbar));
    }
  }

  // ---- head: out[b, :, m0..m0+127] from final h (linear in Gs=buf1) ----
  __syncthreads();
  float* Ws = (float*)Ct;                 // 6192B at buf0 start
  for (int idx = tid; idx < 1548; idx += 256)
    Ws[idx] = (idx < 1536) ? Whead[idx] : bhead[idx - 1536];
  __syncthreads();
  {
    int n = tid & 127, hf = tid >> 7;
    float pa[12];
#pragma unroll
    for (int o = 0; o < 12; ++o) pa[o] = 0.f;
    const f16* Hfin = (const f16*)Gs;
    for (int h = hf * 64; h < hf * 64 + 64; ++h) {
      float v = (float)Hfin[h * 128 + n];
#pragma unroll
      for (int o = 0; o < 12; ++o) pa[o] = fmaf(v, Ws[h * 12 + o], pa[o]);
    }
    float* P = (float*)(sm + 16384);      // 12288B in buf0 tail (no Ws overlap)
#pragma unroll
    for (int o = 0; o < 12; ++o) P[(n * 2 + hf) * 12 + o] = pa[o];
    __syncthreads();
    if (hf == 0) {
#pragma unroll
      for (int o = 0; o < 12; ++o)
        out[(size_t)b * 6144 + o * 512 + m0 + n] =
            P[n * 24 + o] + P[n * 24 + 12 + o] + Ws[1536 + o];
    }
  }
}

// ---------- setup kernels (one-time) ----------
__device__ __forceinline__ void stage128x64(const f16* src, int row0, int ld, int k0,
                                            f16* lds, int tid) {
  int wid = tid >> 6;
#pragma unroll
  for (int q = 0; q < 4; ++q) {
    int lin = q * 4096 + tid * 16;
    int row = lin >> 7;
    int ch = (lin >> 4) & 7;
    int sch = ch ^ (row & 7);
    gload16(src + (size_t)(row0 + row) * ld + k0 + sch * 8,
            (char*)lds + q * 4096 + wid * 1024);
  }
}

__global__ __launch_bounds__(256, 2)
void gemm512(const f16* __restrict__ A, const f16* __restrict__ B,
             f16* __restrict__ C) {
  __shared__ __align__(16) char sm[34816];
  f16* As = (f16*)sm;
  f16* Bs = (f16*)(sm + 16384);
  const int tid = threadIdx.x;
  const int lane = tid & 63;
  const int g = lane >> 4, r = lane & 15;
  const int wid = tid >> 6;
  const int wm = (wid >> 1) * 64, wn = (wid & 1) * 64;
  const int m0 = blockIdx.y * 128;
  const int n0 = blockIdx.x * 128;
  f32x4 acc[4][4] = {};
  for (int kt = 0; kt < 8; ++kt) {
    stage128x64(A, m0, 512, kt * 64, As, tid);
    stage128x64(B, n0, 512, kt * 64, Bs, tid);
    __syncthreads();
#pragma unroll
    for (int kk = 0; kk < 2; ++kk) {
      f16x8 af[4], bf[4];
#pragma unroll
      for (int i = 0; i < 4; ++i) af[i] = frag64(As, wm + i * 16 + r, (kk << 2) | g);
#pragma unroll
      for (int j = 0; j < 4; ++j) bf[j] = frag64(Bs, wn + j * 16 + r, (kk << 2) | g);
#pragma unroll
      for (int i = 0; i < 4; ++i)
#pragma unroll
        for (int j = 0; j < 4; ++j)
          acc[i][j] = MFMA(af[i], bf[j], acc[i][j]);
    }
    __syncthreads();
  }
  f16* Ctl = (f16*)sm;
#pragma unroll
  for (int i = 0; i < 4; ++i)
#pragma unroll
    for (int j = 0; j < 4; ++j) {
      int col = wn + j * 16 + r;
#pragma unroll
      for (int q = 0; q < 4; ++q) {
        int row = wm + i * 16 + g * 4 + q;
        Ctl[row * 136 + col] = (f16)acc[i][j][q];
      }
    }
  __syncthreads();
  f16* Cb = C + (size_t)blockIdx.x * 65536;
#pragma unroll
  for (int p = 0; p < 8; ++p) {
    int row = p * 16 + (tid >> 4);
    int c0 = (tid & 15) * 8;
    f16x8 v = *(const f16x8*)&Ctl[row * 136 + c0];
    *(f16x8*)&Cb[(size_t)(m0 + row) * 128 + c0] = v;
  }
}

__global__ void m12k(const float* __restrict__ E, const float* __restrict__ W1,
                     const float* __restrict__ W2, float* __restrict__ M1,
                     float* __restrict__ M2) {
  int idx = blockIdx.x * 256 + threadIdx.x;
  if (idx >= 16384) return;
  int which = idx >> 13;
  int rem = idx & 8191;
  int n = rem >> 4, j = rem & 15;
  const float* W = which ? W2 : W1;
  float s = 0.f;
#pragma unroll
  for (int k = 0; k < 16; ++k) s += E[n * 16 + k] * W[k * 16 + j];
  (which ? M2 : M1)[n * 16 + j] = s;
}

__global__ __launch_bounds__(256)
void softA(const float* __restrict__ M1, const float* __restrict__ M2,
           f16* __restrict__ A16) {
  __shared__ float M2s[8192];
  __shared__ float m1s[16];
  __shared__ float red[8];
  int i = blockIdx.x, tid = threadIdx.x;
  for (int q = tid; q < 8192; q += 256) M2s[q] = M2[q];
  if (tid < 16) m1s[tid] = M1[i * 16 + tid];
  __syncthreads();
  float s0 = 0.f, s1 = 0.f;
#pragma unroll
  for (int k = 0; k < 16; ++k) {
    float a = m1s[k];
    s0 += a * M2s[tid * 16 + k];
    s1 += a * M2s[(tid + 256) * 16 + k];
  }
  s0 = fmaxf(s0, 0.f);
  s1 = fmaxf(s1, 0.f);
  float m = fmaxf(s0, s1);
  for (int o = 32; o > 0; o >>= 1) m = fmaxf(m, __shfl_xor(m, o));
  if ((tid & 63) == 0) red[tid >> 6] = m;
  __syncthreads();
  m = fmaxf(fmaxf(red[0], red[1]), fmaxf(red[2], red[3]));
  float e0 = expf(s0 - m), e1 = expf(s1 - m);
  float ss = e0 + e1;
  for (int o = 32; o > 0; o >>= 1) ss += __shfl_xor(ss, o);
  __syncthreads();
  if ((tid & 63) == 0) red[4 + (tid >> 6)] = ss;
  __syncthreads();
  ss = (red[4] + red[5]) + (red[6] + red[7]);
  float inv = 1.f / ss;
  A16[(size_t)i * 512 + tid] = (f16)(e0 * inv);
  A16[(size_t)i * 512 + tid + 256] = (f16)(e1 * inv);
}

__global__ void wTk(const float* __restrict__ Wz, const float* __restrict__ Wr,
                    const float* __restrict__ Wh, f16* __restrict__ WzT,
                    f16* __restrict__ WrT, f16* __restrict__ WhT) {
  int idx = blockIdx.x * 256 + threadIdx.x;
  if (idx >= 49152) return;
  int w = idx / 16384;
  int rem = idx & 16383;
  int hp = rem >> 7, k = rem & 127;
  const float* S = (w == 0) ? Wz : ((w == 1) ? Wr : Wh);
  f16* D = (w == 0) ? WzT : ((w == 1) ? WrT : WhT);
  D[hp * 128 + k] = (f16)S[(2 + k) * 128 + hp];
}

__global__ void xTk(const float* __restrict__ X, f16* __restrict__ XTT) {
  int idx = blockIdx.x * 256 + threadIdx.x;
  if (idx >= 786432) return;
  int m = idx & 511;
  int bt = idx >> 9;
  float x0 = X[(size_t)idx * 2];
  float x1 = X[(size_t)idx * 2 + 1];
  XTT[(size_t)(bt * 2 + 0) * 512 + m] = (f16)x0;
  XTT[(size_t)(bt * 2 + 1) * 512 + m] = (f16)x1;
}

extern "C" void kernel_launch(void* const* d_in, const int* in_sizes, int n_in,
                              void* d_out, int out_size, void* d_ws, size_t ws_size,
                              hipStream_t stream) {
  (void)in_sizes; (void)n_in; (void)out_size; (void)ws_size;
  const float* X = (const float*)d_in[0];
  const float* E = (const float*)d_in[1];
  const float* W1 = (const float*)d_in[2];
  const float* W2 = (const float*)d_in[3];
  const float* Wz = (const float*)d_in[4];
  const float* bz = (const float*)d_in[5];
  const float* Wr = (const float*)d_in[6];
  const float* br = (const float*)d_in[7];
  const float* Wh = (const float*)d_in[8];
  const float* bh = (const float*)d_in[9];
  const float* Whead = (const float*)d_in[10];
  const float* bhead = (const float*)d_in[11];
  float* out = (float*)d_out;
  char* ws = (char*)d_ws;

  f16* A16 = (f16*)(ws + 0);           // 512x512
  f16* XTT = (f16*)(ws + 524288);      // 3072x512
  f16* AX  = (f16*)(ws + 3670016);     // [24 tiles][512][128]
  f16* Ha  = (f16*)(ws + 6815744);     // [64][128][512]
  f16* Hb  = (f16*)(ws + 15204352);
  f16* RH  = (f16*)(ws + 23592960);    // [64][128][512]
  f16* WzT = (f16*)(ws + 31981568);    // 128x128 f16
  f16* WrT = (f16*)(ws + 32014336);
  f16* WhT = (f16*)(ws + 32047104);
  float* M1 = (float*)(ws + 32079872);
  float* M2 = (float*)(ws + 32112640);
  unsigned* bar = (unsigned*)(ws + 32145408);  // 64 groups x 64B

  hipMemsetAsync(Ha, 0, 8388608, stream);
  hipMemsetAsync(bar, 0, 16384, stream);
  m12k<<<64, 256, 0, stream>>>(E, W1, W2, M1, M2);
  softA<<<512, 256, 0, stream>>>(M1, M2, A16);
  wTk<<<192, 256, 0, stream>>>(Wz, Wr, Wh, WzT, WrT, WhT);
  xTk<<<3072, 256, 0, stream>>>(X, XTT);
  gemm512<<<dim3(24, 4), 256, 0, stream>>>(A16, XTT, AX);
  persist<<<256, 256, 0, stream>>>(A16, AX, WzT, WrT, WhT, Wz, bz, Wr, br, Wh, bh,
                                   Whead, bhead, Ha, Hb, RH, bar, out);
}

// Round 15
// 716.410 us; speedup vs baseline: 2.5419x; 1.1353x over previous
//
#include <hip/hip_runtime.h>

typedef _Float16 f16;
typedef _Float16 f16x8 __attribute__((ext_vector_type(8)));
typedef float f32x4 __attribute__((ext_vector_type(4)));

typedef const __attribute__((address_space(1))) void GV;
typedef __attribute__((address_space(3))) void LV;

__device__ __forceinline__ void gload16(const void* g, void* l) {
  __builtin_amdgcn_global_load_lds((GV*)g, (LV*)l, 16, 0, 0);
}

#define WAIT_VM0() asm volatile("s_waitcnt vmcnt(0)" ::: "memory")

// coherent-point access: bypass L1+L2 both sides
__device__ __forceinline__ f16x8 ntload16(const f16* p) {
  f16x8 v;
  asm volatile("global_load_dwordx4 %0, %1, off sc0 sc1" : "=v"(v) : "v"(p) : "memory");
  return v;
}
__device__ __forceinline__ void ntstore16(f16* p, f16x8 v) {
  asm volatile("global_store_dwordx4 %0, %1, off sc0 sc1" :: "v"(p), "v"(v) : "memory");
}

// R4/R11-PROVEN rendezvous: relaxed device-scope atomicAdd + sc0sc1 spin
// (tid 0 only; load+waitcnt fused in ONE asm). No cache maintenance.
__device__ __forceinline__ void group_sync(unsigned* bar, unsigned target) {
  __syncthreads();  // drains vmcnt: all prior sc0sc1 stores are at the IC
  if (threadIdx.x == 0) {
    atomicAdd(bar, 1u);
    int guard = 0;
    while (1) {
      unsigned v;
      asm volatile("global_load_dword %0, %1, off sc0 sc1\n\ts_waitcnt vmcnt(0)"
                   : "=v"(v) : "v"(bar) : "memory");
      if (v >= target || ++guard > (1 << 22)) break;
      __builtin_amdgcn_s_sleep(8);
    }
  }
  __syncthreads();
}

// ---- fragment helpers ----
__device__ __forceinline__ f16x8 frag64(const f16* T, int row, int chunk) {
  int ch = chunk ^ (row & 7);
  return *(const f16x8*)((const char*)T + row * 128 + ch * 16);
}
__device__ __forceinline__ f16x8 frag128(const f16* T, int row, int chunk) {
  int ch = chunk ^ (row & 15);
  return *(const f16x8*)((const char*)T + row * 256 + ch * 16);
}
__device__ __forceinline__ f16* elem128(f16* T, int row, int col) {
  return (f16*)((char*)T + row * 256 + (((col >> 3) ^ (row & 15)) << 4) + (col & 7) * 2);
}

#define MFMA(a, b, c) __builtin_amdgcn_mfma_f32_16x16x32_f16(a, b, c, 0, 0, 0)

__device__ __forceinline__ float sigm(float v) {
  return __builtin_amdgcn_rcpf(1.f + __expf(-v));
}
__device__ __forceinline__ float tanh_(float v) {
  return 1.f - 2.f * __builtin_amdgcn_rcpf(1.f + __expf(2.f * v));
}

// stage one 64-wide K-chunk with 512 threads: per thread 2 A-loads (LDS DMA)
// + 2 B-loads (sc0sc1 -> regs). A/B tiles both [128][64] f16 = 16KB each.
__device__ __forceinline__ void issue64(const f16* Ab, const f16* Bb, int k0,
                                        char* bufA, f16x8 (&c)[2],
                                        const size_t (&offs)[2], int wid) {
#pragma unroll
  for (int q = 0; q < 2; ++q)
    gload16(Ab + k0 + offs[q], bufA + q * 8192 + wid * 1024);
#pragma unroll
  for (int q = 0; q < 2; ++q)
    c[q] = ntload16(Bb + k0 + offs[q]);
}
__device__ __forceinline__ void wr64(char* bufB, const f16x8 (&c)[2], int tb) {
#pragma unroll
  for (int q = 0; q < 2; ++q)
    *(f16x8*)(bufB + q * 8192 + tb) = c[q];
}
// per-wave 64x32 output slice: acc[4][2]
__device__ __forceinline__ void comp64(const char* buf, int wm, int wn, int g, int r,
                                       f32x4 (&acc)[4][2]) {
  const f16* Ta = (const f16*)buf;
  const f16* Tb = (const f16*)(buf + 16384);
#pragma unroll
  for (int kk = 0; kk < 2; ++kk) {
    f16x8 af[4], bf[2];
#pragma unroll
    for (int i = 0; i < 4; ++i) af[i] = frag64(Ta, wm + i * 16 + r, (kk << 2) | g);
#pragma unroll
    for (int j = 0; j < 2; ++j) bf[j] = frag64(Tb, wn + j * 16 + r, (kk << 2) | g);
#pragma unroll
    for (int i = 0; i < 4; ++i)
#pragma unroll
      for (int j = 0; j < 2; ++j)
        acc[i][j] = MFMA(af[i], bf[j], acc[i][j]);
  }
}

// K=512 GEMM: 8 x 64-wide chunks, 2 ping-pong buffers, R4 discipline:
// issue k+1, compute k, WAIT_VM0 + B-write, __syncthreads per stage.
__device__ __forceinline__ void phase1(const f16* At, const f16* Bb, char* sm,
    const size_t (&offs)[2], int wid, int wm, int wn, int g, int r,
    f32x4 (&acc)[4][2]) {
  const int tid = threadIdx.x;
  const int tb = tid * 16;
  f16x8 c[2];
  issue64(At, Bb, 0, sm, c, offs, wid);
  WAIT_VM0();
  wr64(sm + 16384, c, tb);
  __syncthreads();
#pragma unroll 1
  for (int kt = 0; kt < 8; ++kt) {
    char* cur = sm + (kt & 1) * 32768;
    char* nxt = sm + ((kt & 1) ^ 1) * 32768;
    if (kt < 7) issue64(At, Bb, (kt + 1) * 64, nxt, c, offs, wid);
    comp64(cur, wm, wn, g, r, acc);
    if (kt < 7) { WAIT_VM0(); wr64(nxt + 16384, c, tb); }
    __syncthreads();
  }
}

// acc(node,h-out) = Gs @ WT^T per wave slice (64x32)
__device__ __forceinline__ void gate_gemm(const f16* Gs, const f16* WT,
                                          int wm, int wn, int g, int r,
                                          f32x4 (&acc)[4][2]) {
#pragma unroll
  for (int kk = 0; kk < 4; ++kk) {
    f16x8 wf[2], af[4];
#pragma unroll
    for (int j = 0; j < 2; ++j)
      wf[j] = *(const f16x8*)&WT[(size_t)(wn + j * 16 + r) * 128 + kk * 32 + g * 8];
#pragma unroll
    for (int i = 0; i < 4; ++i) af[i] = frag128(Gs, wm + i * 16 + r, (kk << 2) | g);
#pragma unroll
    for (int i = 0; i < 4; ++i)
#pragma unroll
      for (int j = 0; j < 2; ++j)
        acc[i][j] = MFMA(af[i], wf[j], acc[i][j]);
  }
}

// 512 threads = 8 waves, each a 64x32 output slice (acc[4][2] = 32 VGPR) ->
// fits the measured ~128-VGPR cap for 512-thread blocks (R12/R13 ERRATUM)
// with NO spills. 256 blocks x 8 waves on 256 CUs = 2 waves/SIMD: co-resident
// waves overlap the sc0sc1 IC/HBM latency (R11/R14 were 1 wave/SIMD).
__global__ __launch_bounds__(512, 1)
void persist(const f16* __restrict__ A16, const f16* __restrict__ AX,
             const f16* __restrict__ WzT, const f16* __restrict__ WrT,
             const f16* __restrict__ WhT,
             const float* __restrict__ Wzf, const float* __restrict__ bz,
             const float* __restrict__ Wrf, const float* __restrict__ br,
             const float* __restrict__ Whf, const float* __restrict__ bh,
             const float* __restrict__ Whead, const float* __restrict__ bhead,
             f16* __restrict__ Ha, f16* __restrict__ Hb,
             f16* __restrict__ RH, unsigned* __restrict__ bar,
             float* __restrict__ out) {
  __shared__ __align__(16) char sm[70656];
  // 0..65536: staging ping-pong (2 x [A 16K | B 16K]).
  // Gs aliases buf1 (32768..65536); Ct aliases buf0 (0..32768).
  f16* Gs = (f16*)(sm + 32768);
  f16* Ct = (f16*)(sm + 0);
  f16* AXs = (f16*)(sm + 65536);     // 512B
  float* wp = (float*)(sm + 66048);  // 9*128 f32 = 4608B

  const int tid = threadIdx.x;
  const int lane = tid & 63;
  const int g = lane >> 4, r = lane & 15;
  const int wid = tid >> 6;                 // 0..7
  const int wm = (wid >> 2) * 64;           // {0,64}
  const int wn = (wid & 3) * 32;            // {0,32,64,96}
  const int b = blockIdx.x >> 2, nc = blockIdx.x & 3;
  const int m0 = nc * 128;

  for (int idx = tid; idx < 1152; idx += 512) {
    int row = idx >> 7, j = idx & 127;
    float v;
    if (row == 0) v = Wzf[j];
    else if (row == 1) v = Wzf[128 + j];
    else if (row == 2) v = bz[j];
    else if (row == 3) v = Wrf[j];
    else if (row == 4) v = Wrf[128 + j];
    else if (row == 5) v = br[j];
    else if (row == 6) v = Whf[j];
    else if (row == 7) v = Whf[128 + j];
    else v = bh[j];
    wp[idx] = v;
  }

  // swizzled per-thread offsets into a [128][64] chunk of an ld=512 source
  size_t offs[2];
#pragma unroll
  for (int q = 0; q < 2; ++q) {
    int lin = q * 8192 + tid * 16;
    int row = lin >> 7;
    int ch = ((lin >> 4) & 7) ^ (row & 7);
    offs[q] = (size_t)row * 512 + ch * 8;
  }

  const f16* Atile = A16 + (size_t)m0 * 512;
  const size_t boff = (size_t)b * 65536;
  f16* rh = RH + boff;
  unsigned* mybar = bar + b * 16;
  unsigned nbar = 0;
  f16x8 zreg[4];
  f16x8 hvreg[4] = {};  // own h slice [hh][node], carried across steps (h0=0)
  __syncthreads();

#pragma unroll 1
  for (int t = 0; t < 24; ++t) {
    const f16* hc = ((t & 1) ? Hb : Ha) + boff;
    f16* hn = ((t & 1) ? Ha : Hb) + boff;
    if (tid < 128) {
      int cf = b * 48 + t * 2;
      const f16* p = AX + (size_t)(cf >> 7) * 65536 + (size_t)(m0 + tid) * 128 + (cf & 127);
      AXs[2 * tid] = p[0];
      AXs[2 * tid + 1] = p[1];
    }
    // ---- phase 1A: G = A @ h ----
    f32x4 acc[4][2] = {};
    phase1(Atile, hc, sm, offs, wid, wm, wn, g, r, acc);
#pragma unroll
    for (int i = 0; i < 4; ++i)
#pragma unroll
      for (int j = 0; j < 2; ++j)
#pragma unroll
        for (int q = 0; q < 4; ++q)
          *elem128(Gs, wm + i * 16 + g * 4 + q, wn + j * 16 + r) = (f16)acc[i][j][q];
    __syncthreads();
    // ---- z gate (stays in registers) ----
    {
      f32x4 az[4][2] = {};
      gate_gemm(Gs, WzT, wm, wn, g, r, az);
#pragma unroll
      for (int i = 0; i < 4; ++i)
#pragma unroll
        for (int j = 0; j < 2; ++j)
#pragma unroll
          for (int q = 0; q < 4; ++q)
            *elem128(Ct, wn + j * 16 + r, wm + i * 16 + g * 4 + q) = (f16)az[i][j][q];
      __syncthreads();
#pragma unroll
      for (int p = 0; p < 4; ++p) {
        int hh = p * 32 + (tid >> 4), c = tid & 15, nl0 = c * 8;
        f16x8 cv = frag128(Ct, hh, c);
        float w0 = wp[hh], w1 = wp[128 + hh], bb = wp[256 + hh];
        f16x8 o;
#pragma unroll
        for (int u = 0; u < 8; ++u) {
          int nl = nl0 + u;
          float gx = (float)AXs[2 * nl] * w0 + (float)AXs[2 * nl + 1] * w1 + bb;
          o[u] = (f16)sigm((float)cv[u] + gx);
        }
        zreg[p] = o;
      }
      __syncthreads();
    }
    // ---- r gate -> rh = r*h (coherent store, group-shared) ----
    {
      f32x4 ar[4][2] = {};
      gate_gemm(Gs, WrT, wm, wn, g, r, ar);
#pragma unroll
      for (int i = 0; i < 4; ++i)
#pragma unroll
        for (int j = 0; j < 2; ++j)
#pragma unroll
          for (int q = 0; q < 4; ++q)
            *elem128(Ct, wn + j * 16 + r, wm + i * 16 + g * 4 + q) = (f16)ar[i][j][q];
      __syncthreads();
#pragma unroll
      for (int p = 0; p < 4; ++p) {
        int hh = p * 32 + (tid >> 4), c = tid & 15, nl0 = c * 8;
        f16x8 cv = frag128(Ct, hh, c);
        f16x8 hv = hvreg[p];
        float w0 = wp[384 + hh], w1 = wp[512 + hh], bb = wp[640 + hh];
        f16x8 o;
#pragma unroll
        for (int u = 0; u < 8; ++u) {
          int nl = nl0 + u;
          float gx = (float)AXs[2 * nl] * w0 + (float)AXs[2 * nl + 1] * w1 + bb;
          float rv = sigm((float)cv[u] + gx);
          o[u] = (f16)(rv * (float)hv[u]);
        }
        ntstore16(&rh[(size_t)hh * 512 + m0 + nl0], o);
      }
      WAIT_VM0();
    }
    group_sync(mybar, 4u * (++nbar));
    // ---- phase 1B: Gh = A @ (r*h) ----
    f32x4 acc2[4][2] = {};
    phase1(Atile, rh, sm, offs, wid, wm, wn, g, r, acc2);
#pragma unroll
    for (int i = 0; i < 4; ++i)
#pragma unroll
      for (int j = 0; j < 2; ++j)
#pragma unroll
        for (int q = 0; q < 4; ++q)
          *elem128(Gs, wm + i * 16 + g * 4 + q, wn + j * 16 + r) = (f16)acc2[i][j][q];
    __syncthreads();
    // ---- h_tilde + update ----
    {
      f32x4 ah[4][2] = {};
      gate_gemm(Gs, WhT, wm, wn, g, r, ah);
#pragma unroll
      for (int i = 0; i < 4; ++i)
#pragma unroll
        for (int j = 0; j < 2; ++j)
#pragma unroll
          for (int q = 0; q < 4; ++q)
            *elem128(Ct, wn + j * 16 + r, wm + i * 16 + g * 4 + q) = (f16)ah[i][j][q];
      __syncthreads();
#pragma unroll
      for (int p = 0; p < 4; ++p) {
        int hh = p * 32 + (tid >> 4), c = tid & 15, nl0 = c * 8;
        f16x8 cv = frag128(Ct, hh, c);
        float w0 = wp[768 + hh], w1 = wp[896 + hh], bb = wp[1024 + hh];
        f16x8 hv = hvreg[p], zv = zreg[p];
        f16x8 o;
#pragma unroll
        for (int u = 0; u < 8; ++u) {
          int nl = nl0 + u;
          float gx = (float)AXs[2 * nl] * w0 + (float)AXs[2 * nl + 1] * w1 + bb;
          float ht = tanh_((float)cv[u] + gx);
          float z = (float)zv[u];
          o[u] = (f16)((1.f - z) * (float)hv[u] + z * ht);
        }
        hvreg[p] = o;
        if (t < 23) {
          ntstore16(&hn[(size_t)hh * 512 + m0 + nl0], o);
        } else {
          *(f16x8*)((char*)Gs + hh * 256 + nl0 * 2) = o;  // final h, linear [h][node]
        }
      }
      if (t < 23) WAIT_VM0();
    }
    if (t < 23) {
      group_sync(mybar, 4u * (++nbar));
    }
  }

  // ---- head: out[b, :, m0..m0+127] from final h (linear in Gs=buf1) ----
  __syncthreads();
  float* Ws = (float*)Ct;                 // 6192B at buf0 start
  for (int idx = tid; idx < 1548; idx += 512)
    Ws[idx] = (idx < 1536) ? Whead[idx] : bhead[idx - 1536];
  __syncthreads();
  {
    int n = tid & 127, qt = tid >> 7;     // 4-way split over h
    float pa[12];
#pragma unroll
    for (int o = 0; o < 12; ++o) pa[o] = 0.f;
    const f16* Hfin = (const f16*)Gs;
    for (int h = qt * 32; h < qt * 32 + 32; ++h) {
      float v = (float)Hfin[h * 128 + n];
#pragma unroll
      for (int o = 0; o < 12; ++o) pa[o] = fmaf(v, Ws[h * 12 + o], pa[o]);
    }
    float* P = (float*)(sm + 8192);       // 24576B in buf0 (8192..32768)
#pragma unroll
    for (int o = 0; o < 12; ++o) P[(n * 4 + qt) * 12 + o] = pa[o];
    __syncthreads();
    if (qt == 0) {
#pragma unroll
      for (int o = 0; o < 12; ++o)
        out[(size_t)b * 6144 + o * 512 + m0 + n] =
            (P[n * 48 + o] + P[n * 48 + 12 + o]) +
            (P[n * 48 + 24 + o] + P[n * 48 + 36 + o]) + Ws[1536 + o];
    }
  }
}

// ---------- setup kernels (one-time) ----------
__device__ __forceinline__ void stage128x64(const f16* src, int row0, int ld, int k0,
                                            f16* lds, int tid) {
  int wid = tid >> 6;
#pragma unroll
  for (int q = 0; q < 4; ++q) {
    int lin = q * 4096 + tid * 16;
    int row = lin >> 7;
    int ch = (lin >> 4) & 7;
    int sch = ch ^ (row & 7);
    gload16(src + (size_t)(row0 + row) * ld + k0 + sch * 8,
            (char*)lds + q * 4096 + wid * 1024);
  }
}

__global__ __launch_bounds__(256, 2)
void gemm512(const f16* __restrict__ A, const f16* __restrict__ B,
             f16* __restrict__ C) {
  __shared__ __align__(16) char sm[34816];
  f16* As = (f16*)sm;
  f16* Bs = (f16*)(sm + 16384);
  const int tid = threadIdx.x;
  const int lane = tid & 63;
  const int g = lane >> 4, r = lane & 15;
  const int wid = tid >> 6;
  const int wm = (wid >> 1) * 64, wn = (wid & 1) * 64;
  const int m0 = blockIdx.y * 128;
  const int n0 = blockIdx.x * 128;
  f32x4 acc[4][4] = {};
  for (int kt = 0; kt < 8; ++kt) {
    stage128x64(A, m0, 512, kt * 64, As, tid);
    stage128x64(B, n0, 512, kt * 64, Bs, tid);
    __syncthreads();
#pragma unroll
    for (int kk = 0; kk < 2; ++kk) {
      f16x8 af[4], bf[4];
#pragma unroll
      for (int i = 0; i < 4; ++i) af[i] = frag64(As, wm + i * 16 + r, (kk << 2) | g);
#pragma unroll
      for (int j = 0; j < 4; ++j) bf[j] = frag64(Bs, wn + j * 16 + r, (kk << 2) | g);
#pragma unroll
      for (int i = 0; i < 4; ++i)
#pragma unroll
        for (int j = 0; j < 4; ++j)
          acc[i][j] = MFMA(af[i], bf[j], acc[i][j]);
    }
    __syncthreads();
  }
  f16* Ctl = (f16*)sm;
#pragma unroll
  for (int i = 0; i < 4; ++i)
#pragma unroll
    for (int j = 0; j < 4; ++j) {
      int col = wn + j * 16 + r;
#pragma unroll
      for (int q = 0; q < 4; ++q) {
        int row = wm + i * 16 + g * 4 + q;
        Ctl[row * 136 + col] = (f16)acc[i][j][q];
      }
    }
  __syncthreads();
  f16* Cb = C + (size_t)blockIdx.x * 65536;
#pragma unroll
  for (int p = 0; p < 8; ++p) {
    int row = p * 16 + (tid >> 4);
    int c0 = (tid & 15) * 8;
    f16x8 v = *(const f16x8*)&Ctl[row * 136 + c0];
    *(f16x8*)&Cb[(size_t)(m0 + row) * 128 + c0] = v;
  }
}

__global__ void m12k(const float* __restrict__ E, const float* __restrict__ W1,
                     const float* __restrict__ W2, float* __restrict__ M1,
                     float* __restrict__ M2) {
  int idx = blockIdx.x * 256 + threadIdx.x;
  if (idx >= 16384) return;
  int which = idx >> 13;
  int rem = idx & 8191;
  int n = rem >> 4, j = rem & 15;
  const float* W = which ? W2 : W1;
  float s = 0.f;
#pragma unroll
  for (int k = 0; k < 16; ++k) s += E[n * 16 + k] * W[k * 16 + j];
  (which ? M2 : M1)[n * 16 + j] = s;
}

__global__ __launch_bounds__(256)
void softA(const float* __restrict__ M1, const float* __restrict__ M2,
           f16* __restrict__ A16) {
  __shared__ float M2s[8192];
  __shared__ float m1s[16];
  __shared__ float red[8];
  int i = blockIdx.x, tid = threadIdx.x;
  for (int q = tid; q < 8192; q += 256) M2s[q] = M2[q];
  if (tid < 16) m1s[tid] = M1[i * 16 + tid];
  __syncthreads();
  float s0 = 0.f, s1 = 0.f;
#pragma unroll
  for (int k = 0; k < 16; ++k) {
    float a = m1s[k];
    s0 += a * M2s[tid * 16 + k];
    s1 += a * M2s[(tid + 256) * 16 + k];
  }
  s0 = fmaxf(s0, 0.f);
  s1 = fmaxf(s1, 0.f);
  float m = fmaxf(s0, s1);
  for (int o = 32; o > 0; o >>= 1) m = fmaxf(m, __shfl_xor(m, o));
  if ((tid & 63) == 0) red[tid >> 6] = m;
  __syncthreads();
  m = fmaxf(fmaxf(red[0], red[1]), fmaxf(red[2], red[3]));
  float e0 = expf(s0 - m), e1 = expf(s1 - m);
  float ss = e0 + e1;
  for (int o = 32; o > 0; o >>= 1) ss += __shfl_xor(ss, o);
  __syncthreads();
  if ((tid & 63) == 0) red[4 + (tid >> 6)] = ss;
  __syncthreads();
  ss = (red[4] + red[5]) + (red[6] + red[7]);
  float inv = 1.f / ss;
  A16[(size_t)i * 512 + tid] = (f16)(e0 * inv);
  A16[(size_t)i * 512 + tid + 256] = (f16)(e1 * inv);
}

__global__ void wTk(const float* __restrict__ Wz, const float* __restrict__ Wr,
                    const float* __restrict__ Wh, f16* __restrict__ WzT,
                    f16* __restrict__ WrT, f16* __restrict__ WhT) {
  int idx = blockIdx.x * 256 + threadIdx.x;
  if (idx >= 49152) return;
  int w = idx / 16384;
  int rem = idx & 16383;
  int hp = rem >> 7, k = rem & 127;
  const float* S = (w == 0) ? Wz : ((w == 1) ? Wr : Wh);
  f16* D = (w == 0) ? WzT : ((w == 1) ? WrT : WhT);
  D[hp * 128 + k] = (f16)S[(2 + k) * 128 + hp];
}

__global__ void xTk(const float* __restrict__ X, f16* __restrict__ XTT) {
  int idx = blockIdx.x * 256 + threadIdx.x;
  if (idx >= 786432) return;
  int m = idx & 511;
  int bt = idx >> 9;
  float x0 = X[(size_t)idx * 2];
  float x1 = X[(size_t)idx * 2 + 1];
  XTT[(size_t)(bt * 2 + 0) * 512 + m] = (f16)x0;
  XTT[(size_t)(bt * 2 + 1) * 512 + m] = (f16)x1;
}

extern "C" void kernel_launch(void* const* d_in, const int* in_sizes, int n_in,
                              void* d_out, int out_size, void* d_ws, size_t ws_size,
                              hipStream_t stream) {
  (void)in_sizes; (void)n_in; (void)out_size; (void)ws_size;
  const float* X = (const float*)d_in[0];
  const float* E = (const float*)d_in[1];
  const float* W1 = (const float*)d_in[2];
  const float* W2 = (const float*)d_in[3];
  const float* Wz = (const float*)d_in[4];
  const float* bz = (const float*)d_in[5];
  const float* Wr = (const float*)d_in[6];
  const float* br = (const float*)d_in[7];
  const float* Wh = (const float*)d_in[8];
  const float* bh = (const float*)d_in[9];
  const float* Whead = (const float*)d_in[10];
  const float* bhead = (const float*)d_in[11];
  float* out = (float*)d_out;
  char* ws = (char*)d_ws;

  f16* A16 = (f16*)(ws + 0);           // 512x512
  f16* XTT = (f16*)(ws + 524288);      // 3072x512
  f16* AX  = (f16*)(ws + 3670016);     // [24 tiles][512][128]
  f16* Ha  = (f16*)(ws + 6815744);     // [64][128][512]
  f16* Hb  = (f16*)(ws + 15204352);
  f16* RH  = (f16*)(ws + 23592960);    // [64][128][512]
  f16* WzT = (f16*)(ws + 31981568);    // 128x128 f16
  f16* WrT = (f16*)(ws + 32014336);
  f16* WhT = (f16*)(ws + 32047104);
  float* M1 = (float*)(ws + 32079872);
  float* M2 = (float*)(ws + 32112640);
  unsigned* bar = (unsigned*)(ws + 32145408);  // 64 groups x 64B

  hipMemsetAsync(Ha, 0, 8388608, stream);
  hipMemsetAsync(bar, 0, 16384, stream);
  m12k<<<64, 256, 0, stream>>>(E, W1, W2, M1, M2);
  softA<<<512, 256, 0, stream>>>(M1, M2, A16);
  wTk<<<192, 256, 0, stream>>>(Wz, Wr, Wh, WzT, WrT, WhT);
  xTk<<<3072, 256, 0, stream>>>(X, XTT);
  gemm512<<<dim3(24, 4), 256, 0, stream>>>(A16, XTT, AX);
  persist<<<256, 512, 0, stream>>>(A16, AX, WzT, WrT, WhT, Wz, bz, Wr, br, Wh, bh,
                                   Whead, bhead, Ha, Hb, RH, bar, out);
}